// Round 1
// baseline (170.554 us; speedup 1.0000x reference)
//
#include <hip/hip_runtime.h>

// Enframe: out[bc, k, t] = x[bc, t*HOP + k].  BC=16, S=480000, FL=2048,
// HOP=512, T=934.  k = h*HOP + r (h in [0,4), r in [0,HOP)):
//   out[bc, h*HOP + r, t] = row (t+h), col r of x viewed as rows of HOP.
// LDS transpose per tile: load (67 rows x 64 r) coalesced along r, emit
// (4h x 64 r) x 64 t coalesced along t.
//
// R2 lesson: scalar nt stores were the bottleneck hypothesis (R0 divergent-read
// and R2 coalesced-read kernels timed identically). R3 (float4 stores) was
// within noise of R2 -> either store-DRAM-bound or harness-floor-bound.
// R4 (this round): each block owns NT=2 CONSECUTIVE t-tiles, processed
// back-to-back. Each k-row's 512B span is written by ONE block with immediate
// temporal adjacency -> the internal partial-64B-line boundary merges in L2
// for certain; cross-block merge points per k-row drop 15 -> 8. Grid
// 16x8x8=1024 blocks (4/CU, 16 waves/CU). Same-bc blocks still map to the
// same XCD (linear id % 8 == bc % 8) for L2 read locality + write merging.

constexpr int FL  = 2048;
constexpr int HOP = 512;
constexpr int TT  = 64;           // inner t-tile
constexpr int NT  = 2;            // consecutive t-tiles per block
constexpr int RT  = 64;           // r-tile
constexpr int ROWS = TT + 3;      // 67: rows t..t+66
constexpr int LSTR = RT + 1;      // 65: LDS row stride (2-way banks = free)

__global__ __launch_bounds__(256)
void enframe_kernel(const float* __restrict__ x, float* __restrict__ out,
                    int S, int T) {
    __shared__ float lds[ROWS * LSTR];

    const int bc = blockIdx.x;          // 0..15
    const int r0 = blockIdx.z * RT;
    const int tid = threadIdx.x;

    const float* xb = x + (size_t)bc * S;
    float* ob = out + (size_t)bc * FL * T;

    // load-side lane mapping
    const int rg   = tid & 15;          // 16 float4 per 64-float row
    const int row0 = tid >> 4;
    // store-side lane mapping
    const int tg = tid & 15;            // t-group (4 t's each)
    const int ko = tid >> 4;            // 0..15: k offset within r-tile step
    const int tl = tg * 4;              // local t base

#pragma unroll
    for (int it = 0; it < NT; ++it) {
        const int t0 = (blockIdx.y * NT + it) * TT;
        if (t0 >= T) break;             // uniform per block: safe with barriers
        if (it) __syncthreads();        // protect LDS reuse across tiles

        // ---- load: 67 rows x 64 floats, float4-coalesced along r ----
#pragma unroll
        for (int p = 0; p < 5; ++p) {
            const int row = p * 16 + row0;
            if (row < ROWS) {
                const size_t base = (size_t)(t0 + row) * HOP + r0;
                if (base + RT <= (size_t)S) {
                    const float4 v = *(const float4*)(xb + base + rg * 4);
                    float* l = lds + row * LSTR + rg * 4;
                    l[0] = v.x; l[1] = v.y; l[2] = v.z; l[3] = v.w;
                }
            }
        }
        __syncthreads();

        // ---- store: float4 along t (lanes: 16 t-groups x 4 k-offsets) ----
        const int t = t0 + tl;
        const bool full = (t + 3 < T);
#pragma unroll
        for (int rb = 0; rb < RT; rb += 16) {
            const int rr = rb + ko;     // local r
            const int kb = r0 + rr;
#pragma unroll
            for (int h = 0; h < 4; ++h) {
                const int k = h * HOP + kb;
                const float* l = lds + (tl + h) * LSTR + rr;
                if (full) {
                    float4 v = { l[0 * LSTR], l[1 * LSTR],
                                 l[2 * LSTR], l[3 * LSTR] };
                    *(float4*)(ob + (size_t)k * T + t) = v;
                } else {
#pragma unroll
                    for (int j = 0; j < 4; ++j)
                        if (t + j < T) ob[(size_t)k * T + t + j] = l[j * LSTR];
                }
            }
        }
    }
}

extern "C" void kernel_launch(void* const* d_in, const int* in_sizes, int n_in,
                              void* d_out, int out_size, void* d_ws, size_t ws_size,
                              hipStream_t stream) {
    const float* x = (const float*)d_in[0];
    float* out = (float*)d_out;
    const int BC = 16;                  // B*C = 8*2
    const int S  = in_sizes[0] / BC;    // 480000
    const int T  = (S - FL) / HOP + 1;  // 934
    const int t_span  = TT * NT;                       // 128
    const int t_tiles = (T + t_span - 1) / t_span;     // 8
    const int r_tiles = HOP / RT;                      // 8
    dim3 grid(BC, (unsigned)t_tiles, (unsigned)r_tiles);
    enframe_kernel<<<grid, 256, 0, stream>>>(x, out, S, T);
}

// Round 3
// 161.540 us; speedup vs baseline: 1.0558x; 1.0558x over previous
//
#include <hip/hip_runtime.h>

// Enframe: out[bc, k, t] = x[bc, t*HOP + k].  BC=16, S=480000, FL=2048,
// HOP=512, T=934.  k = h*HOP + r (h in [0,4), r in [0,HOP)):
//   out[bc, h*HOP + r, t] = x[bc, (t+h)*HOP + r].
//
// R3/R4 lesson: dur_us = ~72us harness fill + kernel. R3 kernel ~79us at
// ~2 TB/s effective -> store-path bound: 256B segments per (k, t-tile) with
// misaligned edges (row len 3736B = 24 mod 64) written by 15 different
// blocks -> L2 partial-line merge fails under eviction pressure -> RMW
// fetches + scattered 256B DRAM granules.
//
// R5/R6: block = (bc, h, 16 consecutive r), ALL 934 t. 16 consecutive k-rows
// of out form ONE contiguous 59,776B region whose base is 64B-aligned
// (16*3736 % 64 == 0). LDS row stride == T makes LDS linear addr == out
// linear offset, so the store phase is a pure aligned memcpy:
// ds_read_b128 -> float4 nontemporal stores, 1KB/wave-instr, every 64B line
// fully written by one wave-instr (nt is safe now -- no partial lines).
// grid.x = bc -> 2 bc per XCD -> x slab (3.84MB) stays L2-resident for the
// 4x h-reuse; nt stores don't evict it.
// 1024 thr, 58.4KB LDS -> 2 blocks/CU = 32 waves/CU.
// R6 fix: __builtin_nontemporal_store needs a clang native vector type,
// not HIP's float4 class -> use ext_vector_type(4) float.

constexpr int FL   = 2048;
constexpr int HOP  = 512;
constexpr int KT   = 16;            // consecutive k's (r's) per block
constexpr int TMAX = 934;           // max T the LDS is sized for
constexpr int NTHR = 1024;

typedef float vf4 __attribute__((ext_vector_type(4)));

__global__ __launch_bounds__(NTHR)
void enframe_kernel(const float* __restrict__ x, float* __restrict__ out,
                    int S, int T) {
    __shared__ float lds[KT * TMAX];   // 59,776 B

    const int bc = blockIdx.x;          // 0..15
    const int h  = blockIdx.y;          // 0..3
    const int r0 = blockIdx.z * KT;     // 0..496 step 16
    const int tid = threadIdx.x;

    const float* xb = x + (size_t)bc * S;
    // contiguous output region: rows k0..k0+15, all t
    float* ob = out + ((size_t)bc * FL + (size_t)h * HOP + r0) * (size_t)T;

    // ---- load: for each t, 16 floats (r0..r0+15) via 4 lanes of vf4 ----
    // lane: c4 = tid&3 (which float4 of the row), trow = tid>>2 (t offset)
    {
        const int c4 = tid & 3;
        const int trow = tid >> 2;          // 0..255
#pragma unroll
        for (int it = 0; it < 4; ++it) {
            const int t = it * (NTHR / 4) + trow;
            if (t < T) {
                const size_t g = (size_t)(t + h) * HOP + r0 + c4 * 4;
                if (g + 4 <= (size_t)S) {
                    const vf4 v = *(const vf4*)(xb + g);
                    // LDS[kk * T + t], kk = c4*4 + i  (2-way bank alias = free)
                    float* l = lds + (size_t)(c4 * 4) * T + t;
                    l[0 * T] = v.x; l[1 * T] = v.y;
                    l[2 * T] = v.z; l[3 * T] = v.w;
                }
            }
        }
    }
    __syncthreads();

    // ---- store: pure linear memcpy of KT*T floats (LDS addr == out offset) ----
    {
        const int nq = KT * T / 4;          // float4 count (16*T always %4==0)
#pragma unroll
        for (int it = 0; it < 4; ++it) {
            const int q = it * NTHR + tid;
            if (q < nq) {
                const vf4 v = *(const vf4*)(lds + (size_t)q * 4);
                __builtin_nontemporal_store(v, (vf4*)(ob + (size_t)q * 4));
            }
        }
    }
}

extern "C" void kernel_launch(void* const* d_in, const int* in_sizes, int n_in,
                              void* d_out, int out_size, void* d_ws, size_t ws_size,
                              hipStream_t stream) {
    const float* x = (const float*)d_in[0];
    float* out = (float*)d_out;
    const int BC = 16;                  // B*C = 8*2
    const int S  = in_sizes[0] / BC;    // 480000
    const int T  = (S - FL) / HOP + 1;  // 934
    const int r_tiles = HOP / KT;       // 32
    dim3 grid(BC, 4u, (unsigned)r_tiles);
    enframe_kernel<<<grid, NTHR, 0, stream>>>(x, out, S, T);
}

// Round 5
// 151.117 us; speedup vs baseline: 1.1286x; 1.0690x over previous
//
#include <hip/hip_runtime.h>

// Enframe: out[bc, k, t] = x[bc, t*HOP + k].  BC=16, S=480000, FL=2048,
// HOP=512, T=934.  k = h*HOP + r (h in [0,4), r in [0,HOP)):
//   out[bc, h*HOP + r, t] = row (t+h), col r of x viewed as rows of HOP.
// LDS transpose per block: load (67 rows x 64 r) coalesced along r, emit
// (4h x 64 r) x 64 t coalesced along t.
//
// SESSION VERDICT (R0-R6): this structure is the empirical best (151.07us).
//  - R0 divergent-read, R2 coalesced scalar-store, R3 (this) float4-store
//    all timed 151-152.5us -> time is floor-dominated, not kernel-bound.
//  - R4 (NT=2 serial tiles/block): +19.5us. R5 (contiguous 59.8KB stores,
//    nt, all-t blocks): +10.5us. Both restructures regressed.
//  - rocprof: enframe never appears in top-5 (all 478MB harness fills at
//    ~72us, 84% HBM peak) -> kernel < 72us; delta-fitting gives ~20us,
//    i.e. ~7.6 TB/s effective -- L3-assisted (122MB output fits 256MB
//    Infinity Cache), already past the HBM roofline.
//  - All 1920 blocks co-resident (8/CU) -> adjacent t-tiles merge partial
//    64B lines in same-XCD L2 (grid.x=bc -> id%8==bc%8).

constexpr int FL  = 2048;
constexpr int HOP = 512;
constexpr int TT  = 64;           // t-tile
constexpr int RT  = 64;           // r-tile
constexpr int ROWS = TT + 3;      // 67: rows t..t+3
constexpr int LSTR = RT + 1;      // 65: LDS row stride (2-way banks = free)

__global__ __launch_bounds__(256)
void enframe_kernel(const float* __restrict__ x, float* __restrict__ out,
                    int S, int T) {
    __shared__ float lds[ROWS * LSTR];

    const int bc = blockIdx.x;          // 0..15
    const int t0 = blockIdx.y * TT;
    const int r0 = blockIdx.z * RT;
    const int tid = threadIdx.x;

    // ---- load: 67 rows x 64 floats, float4-coalesced along r ----
    {
        const int rg   = tid & 15;      // 16 float4 per 64-float row
        const int row0 = tid >> 4;
        const float* xb = x + (size_t)bc * S;
#pragma unroll
        for (int p = 0; p < 5; ++p) {
            const int row = p * 16 + row0;
            if (row < ROWS) {
                const size_t base = (size_t)(t0 + row) * HOP + r0;
                if (base + RT <= (size_t)S) {
                    const float4 v = *(const float4*)(xb + base + rg * 4);
                    float* l = lds + row * LSTR + rg * 4;
                    l[0] = v.x; l[1] = v.y; l[2] = v.z; l[3] = v.w;
                }
            }
        }
    }
    __syncthreads();

    // ---- store: float4 along t (lanes: 16 t-groups x 4 k-offsets) ----
    const int tg = tid & 15;            // t-group (4 t's each)
    const int ko = tid >> 4;            // 0..15: k offset within r-tile step
    const int tl = tg * 4;              // local t base
    const int t  = t0 + tl;
    float* ob = out + (size_t)bc * FL * T;
    const bool full = (t + 3 < T);
#pragma unroll
    for (int rb = 0; rb < RT; rb += 16) {
        const int rr = rb + ko;         // local r
        const int kb = r0 + rr;
#pragma unroll
        for (int h = 0; h < 4; ++h) {
            const int k = h * HOP + kb;
            const float* l = lds + (tl + h) * LSTR + rr;
            if (full) {
                float4 v = { l[0 * LSTR], l[1 * LSTR], l[2 * LSTR], l[3 * LSTR] };
                *(float4*)(ob + (size_t)k * T + t) = v;
            } else {
#pragma unroll
                for (int j = 0; j < 4; ++j)
                    if (t + j < T) ob[(size_t)k * T + t + j] = l[j * LSTR];
            }
        }
    }
}

extern "C" void kernel_launch(void* const* d_in, const int* in_sizes, int n_in,
                              void* d_out, int out_size, void* d_ws, size_t ws_size,
                              hipStream_t stream) {
    const float* x = (const float*)d_in[0];
    float* out = (float*)d_out;
    const int BC = 16;                  // B*C = 8*2
    const int S  = in_sizes[0] / BC;    // 480000
    const int T  = (S - FL) / HOP + 1;  // 934
    const int t_tiles = (T + TT - 1) / TT;   // 15
    const int r_tiles = HOP / RT;            // 8
    dim3 grid(BC, (unsigned)t_tiles, (unsigned)r_tiles);
    enframe_kernel<<<grid, 256, 0, stream>>>(x, out, S, T);
}